// Round 12
// baseline (484.690 us; speedup 1.0000x reference)
//
#include <hip/hip_runtime.h>
#include <hip/hip_bf16.h>

// Problem constants (from reference setup_inputs)
#define NB   8
#define NN   16384
#define NK   9
#define NCF  64          // feature channels
#define NCIN 66          // 2 + 64 concat channels
#define NCO  64
#define JTOT (NCIN * NK) // 594
#define KPAD 608         // 19 * 32 (MFMA K-steps)
#define ROWE 610         // LDS wf row length in bf16 elems (odd dword stride -> conflict-free)
#define ROWU (ROWE / 2)  // 305 uints per row
#define MT   32          // points per block
#define WVR  83          // wvs row stride in dwords (odd -> conflict-free)

typedef __attribute__((ext_vector_type(8))) short frag8;  // 8 bf16 (4 VGPRs)
typedef __attribute__((ext_vector_type(4))) float frag4;  // 4 fp32 acc

__device__ __forceinline__ float leakyf(float x) { return fmaxf(x, 0.1f * x); }

// bf16 RNE — the proven numerics path (absmax 0.125).
// R10 (465.4 µs, passed): direct per-thread feat loads, no staging barriers.
// R11 delta: WeightNet 8-way DE-DUP. All 8 g-threads of a point computed the
// identical wv[9][9] (~1215 VALU instr each = 51% of the kernel's VALU).
// wv[o][k] is per-k independent -> thread (p,g) computes only k=g (g==7 also
// k=8; balances g==0's xy-channel work), publishes to wvs LDS, barrier, 81
// ds_read readback. Same ops per wv entry, f32 exact through LDS -> output
// unchanged. Cost: +10.6KB LDS (3 blocks/CU, was 4) + ~90 LDS ops vs ~-990
// VALU instr/thread.
__device__ __forceinline__ unsigned short f2bf(float x) {
  __hip_bfloat16 h = __float2bfloat16(x);
  unsigned short us;
  __builtin_memcpy(&us, &h, 2);
  return us;
}

// Repack lin_w [64][594] fp32 (row co, col o*66+c) into bf16 lb[co][j], j = c*9+o, zero-padded to 608.
__global__ void prep_lb_kernel(const float* __restrict__ lin_w, unsigned short* __restrict__ lb) {
  int idx = blockIdx.x * 256 + threadIdx.x;
  if (idx >= NCO * KPAD) return;
  int co = idx / KPAD;
  int j  = idx - co * KPAD;
  float v = 0.f;
  if (j < JTOT) {
    int c = j / NK;
    int o = j - c * NK;
    v = lin_w[co * JTOT + o * NCIN + c];
  }
  lb[idx] = f2bf(v);
}

__global__ __launch_bounds__(256) void pointconv_kernel(
    const float* __restrict__ xy,   // [8][2][16384][9]
    const float* __restrict__ feat, // [8][64][16384][9]
    const float* __restrict__ w1,   // [9][2]
    const float* __restrict__ b1,   // [9]
    const float* __restrict__ w2,   // [9][9]
    const float* __restrict__ b2,   // [9]
    const unsigned short* __restrict__ lb, // bf16 [64][608]
    const float* __restrict__ lin_b,       // [64]
    float* __restrict__ out) {             // [8][64][16384]
  __shared__ unsigned short wfs[MT * ROWE]; // 39,040 B
  __shared__ float wvs[MT * WVR];           // 10,624 B -> 49,664 total, 3 blocks/CU

  const int t    = threadIdx.x;
  const int p    = t & 31;          // point within tile
  const int g    = t >> 5;          // channel group 0..7 (8 channels each)
  const int lane = t & 63;
  const int wvid = t >> 6;          // wave id 0..3
  const int b    = blockIdx.x >> 9; // 512 tiles per batch
  const int n0   = (blockIdx.x & 511) << 5;
  const int n    = n0 + p;

  // ---- xy loads (registers; all threads load full rows — g0 needs them for
  // the xy concat channels, and keeping the pattern identical minimizes risk) ----
  float x0[9], x1[9];
  {
    const float* x0p = xy + (((size_t)b * 2 + 0) * NN + n) * NK;
    const float* x1p = xy + (((size_t)b * 2 + 1) * NN + n) * NK;
#pragma unroll
    for (int k = 0; k < NK; ++k) { x0[k] = x0p[k]; x1[k] = x1p[k]; }
  }

  // ---- Phase 1a: WeightNet k-slice. wv[o][k] depends only on x0[k],x1[k] ->
  // per-wave only 2 (wave3: 3) of the 9 unrolled iterations have any active
  // lanes; the rest are execz-skipped. Ops per computed entry are IDENTICAL
  // to the monolithic version -> same f32 values. ----
#pragma unroll
  for (int k = 0; k < NK; ++k) {
    if (k == g || (k == 8 && g == 7)) {
      float h[9];
#pragma unroll
      for (int o = 0; o < 9; ++o)
        h[o] = leakyf(w1[2 * o] * x0[k] + w1[2 * o + 1] * x1[k] + b1[o]);
#pragma unroll
      for (int o = 0; o < 9; ++o) {
        float s = b2[o];
#pragma unroll
        for (int o2 = 0; o2 < 9; ++o2) s += w2[o * 9 + o2] * h[o2];
        wvs[p * WVR + o * 9 + k] = leakyf(s);
      }
    }
  }
  // g==1's zero-pad needs no wv — do it before the barrier to overlap.
  if (g == 1) {
#pragma unroll
    for (int m = 0; m < KPAD - JTOT; ++m) wfs[p * ROWE + JTOT + m] = 0;
  }
  __syncthreads();  // publish wvs

  // ---- Readback: 81 dwords/thread. Lanes with same p broadcast (free);
  // across p stride 83 dwords (odd) -> conflict-free. Static indices ->
  // stays in VGPRs (rule #20). ----
  float wv[9][9];
#pragma unroll
  for (int o = 0; o < 9; ++o)
#pragma unroll
    for (int k = 0; k < NK; ++k) wv[o][k] = wvs[p * WVR + o * 9 + k];

  // ---- xy channels (concat c=0,1) from registers; math identical ----
  if (g == 0) {
#pragma unroll
    for (int cc = 0; cc < 2; ++cc) {
#pragma unroll
      for (int o = 0; o < 9; ++o) {
        float s = wv[o][0] * (cc ? x1[0] : x0[0]);
#pragma unroll
        for (int k = 1; k < NK; ++k) s += wv[o][k] * (cc ? x1[k] : x0[k]);
        wfs[p * ROWE + cc * 9 + o] = f2bf(s);
      }
    }
  }

  // ---- Phase 1b: 8 feat channels per thread, direct global->register
  // (R10 verbatim). Channel cc -> feat channel cc*8+g -> concat c = 2+cc*8+g. ----
  {
    const float* fbase = feat + (((size_t)b * NCF + g) * NN + (size_t)n) * NK;
#pragma unroll
    for (int cc = 0; cc < 8; ++cc) {
      const float* fp = fbase + (size_t)(cc * 8) * ((size_t)NN * NK);
      float f[9];
#pragma unroll
      for (int k = 0; k < NK; ++k) f[k] = fp[k];
      const int c = 2 + cc * 8 + g;
      unsigned short* wr = wfs + p * ROWE + c * 9;
#pragma unroll
      for (int o = 0; o < 9; ++o) {
        float s = wv[o][0] * f[0];
#pragma unroll
        for (int k = 1; k < NK; ++k) s += wv[o][k] * f[k];
        wr[o] = f2bf(s);
      }
    }
  }

  __syncthreads();  // publish wfs for phase 2

  // ---- Phase 2: [32 pts x 608] @ [608 x 64 co] via mfma_f32_16x16x32_bf16 ----
  const unsigned int* wfu = (const unsigned int*)wfs;
  const int r    = wvid & 1;     // row-tile: points [16r, 16r+16)
  const int hh   = wvid >> 1;    // col half: co tiles {2hh, 2hh+1}
  const int col  = lane & 15;
  const int q    = lane >> 4;

  frag4 acc[2];
#pragma unroll
  for (int ct = 0; ct < 2; ++ct) acc[ct] = frag4{0.f, 0.f, 0.f, 0.f};

  const int arow_u = (16 * r + col) * ROWU;

  for (int s = 0; s < KPAD / 32; ++s) {
    const int k0 = 32 * s;
    union { unsigned int u[4]; frag8 v; } ua;
    const int abase = arow_u + ((k0 + q * 8) >> 1);
    ua.u[0] = wfu[abase + 0];
    ua.u[1] = wfu[abase + 1];
    ua.u[2] = wfu[abase + 2];
    ua.u[3] = wfu[abase + 3];
#pragma unroll
    for (int ct = 0; ct < 2; ++ct) {
      const frag8* bp = (const frag8*)(lb + ((2 * hh + ct) * 16 + col) * KPAD + k0 + q * 8);
      acc[ct] = __builtin_amdgcn_mfma_f32_16x16x32_bf16(ua.v, *bp, acc[ct], 0, 0, 0);
    }
  }

  // ---- Epilogue: bias + leaky, float4 stores (D: col -> co, row = q*4+reg -> point) ----
  float* outbase = out + ((size_t)b * NCO) * NN;
  const int nrow = n0 + 16 * r + q * 4;
#pragma unroll
  for (int ct = 0; ct < 2; ++ct) {
    const int co = (2 * hh + ct) * 16 + col;
    const float bias = lin_b[co];
    float4 v;
    v.x = leakyf(acc[ct][0] + bias);
    v.y = leakyf(acc[ct][1] + bias);
    v.z = leakyf(acc[ct][2] + bias);
    v.w = leakyf(acc[ct][3] + bias);
    *(float4*)(outbase + (size_t)co * NN + nrow) = v;
  }
}

extern "C" void kernel_launch(void* const* d_in, const int* in_sizes, int n_in,
                              void* d_out, int out_size, void* d_ws, size_t ws_size,
                              hipStream_t stream) {
  const float* xy    = (const float*)d_in[0];
  const float* feat  = (const float*)d_in[1];
  const float* w1    = (const float*)d_in[2];
  const float* b1    = (const float*)d_in[3];
  const float* w2    = (const float*)d_in[4];
  const float* b2    = (const float*)d_in[5];
  const float* lw    = (const float*)d_in[6];
  const float* lbias = (const float*)d_in[7];
  float* out = (float*)d_out;
  unsigned short* lb = (unsigned short*)d_ws; // 64*608*2 = 77824 B

  prep_lb_kernel<<<(NCO * KPAD + 255) / 256, 256, 0, stream>>>(lw, lb);
  pointconv_kernel<<<NB * (NN / MT), 256, 0, stream>>>(
      xy, feat, w1, b1, w2, b2, lb, lbias, out);
}